// Round 1
// baseline (2073.237 us; speedup 1.0000x reference)
//
#include <hip/hip_runtime.h>
#include <cstdint>
#include <cstddef>

#define B_   16
#define D_   192
#define TY   2048
#define TX   512
#define NEG_INF_F (-1e9f)

// ======================= K1: nc14[b,x] = nc1 + nc4 =======================
__global__ __launch_bounds__(256)
void nc14_kernel(const float* __restrict__ m_p,
                 const float* __restrict__ logs_p,
                 float* __restrict__ nc14) {
    int gid = blockIdx.x * 256 + threadIdx.x;       // 0..8191  (B*TX)
    int b = gid >> 9;
    int x = gid & 511;
    const float c = -0.9189385332046727f;           // -0.5*log(2*pi)
    const float* lp = logs_p + (size_t)b * D_ * TX + x;
    const float* mp = m_p    + (size_t)b * D_ * TX + x;
    float acc1 = 0.f, acc2 = 0.f;
    for (int d = 0; d < D_; ++d) {
        float l = lp[(size_t)d * TX];
        float m = mp[(size_t)d * TX];
        float s = __expf(-2.f * l);
        acc1 += c - l;
        acc2 += m * m * s;
    }
    nc14[gid] = acc1 - 0.5f * acc2;
}

// ======================= K2: fp32 GEMM for neg_cent =======================
// C[b,y,x] = nc14[b,x] + sum_d( (-0.5 z^2)[d,y]*s[d,x] + z[d,y]*(m*s)[d,x] )
#define BM 128
#define BN 64
#define BK 16

__global__ __launch_bounds__(256)
void gemm_kernel(const float* __restrict__ z_p,
                 const float* __restrict__ m_p,
                 const float* __restrict__ logs_p,
                 const float* __restrict__ nc14,
                 float* __restrict__ out) {
    __shared__ float a_z [BK][BM];
    __shared__ float a_z2[BK][BM];
    __shared__ float sb_s [BK][BN];
    __shared__ float sb_ms[BK][BN];

    const int b  = blockIdx.z;
    const int m0 = blockIdx.y * BM;
    const int n0 = blockIdx.x * BN;
    const int tid = threadIdx.x;
    const int tx = tid & 15;      // 16 cols-of-4
    const int ty = tid >> 4;      // 16 rows-of-8

    const float* zb = z_p    + (size_t)b * D_ * TY;
    const float* mb = m_p    + (size_t)b * D_ * TX;
    const float* lb = logs_p + (size_t)b * D_ * TX;

    float acc[8][4];
    #pragma unroll
    for (int i = 0; i < 8; ++i)
        #pragma unroll
        for (int j = 0; j < 4; ++j) acc[i][j] = 0.f;

    for (int k0 = 0; k0 < D_; k0 += BK) {
        // ---- stage A tile: BK x BM (z and -0.5 z^2), 2 float4 per thread
        #pragma unroll
        for (int q = 0; q < 2; ++q) {
            int idx = tid * 2 + q;            // 0..511
            int kk = idx >> 5;                // 16 rows
            int yy = (idx & 31) * 4;          // 128 cols
            float4 v = *(const float4*)(zb + (size_t)(k0 + kk) * TY + m0 + yy);
            *(float4*)&a_z[kk][yy] = v;
            float4 w;
            w.x = -0.5f * v.x * v.x; w.y = -0.5f * v.y * v.y;
            w.z = -0.5f * v.z * v.z; w.w = -0.5f * v.w * v.w;
            *(float4*)&a_z2[kk][yy] = w;
        }
        // ---- stage B tile: BK x BN (s and m*s), 1 float4 per thread each
        {
            int kk = tid >> 4;
            int xx = (tid & 15) * 4;
            float4 lg = *(const float4*)(lb + (size_t)(k0 + kk) * TX + n0 + xx);
            float4 mm = *(const float4*)(mb + (size_t)(k0 + kk) * TX + n0 + xx);
            float4 s;
            s.x = __expf(-2.f * lg.x); s.y = __expf(-2.f * lg.y);
            s.z = __expf(-2.f * lg.z); s.w = __expf(-2.f * lg.w);
            *(float4*)&sb_s[kk][xx] = s;
            float4 ms;
            ms.x = mm.x * s.x; ms.y = mm.y * s.y;
            ms.z = mm.z * s.z; ms.w = mm.w * s.w;
            *(float4*)&sb_ms[kk][xx] = ms;
        }
        __syncthreads();
        #pragma unroll
        for (int kk = 0; kk < BK; ++kk) {
            float az[8], a2[8], bs[4], bm[4];
            *(float4*)&az[0] = *(const float4*)&a_z [kk][ty * 8];
            *(float4*)&az[4] = *(const float4*)&a_z [kk][ty * 8 + 4];
            *(float4*)&a2[0] = *(const float4*)&a_z2[kk][ty * 8];
            *(float4*)&a2[4] = *(const float4*)&a_z2[kk][ty * 8 + 4];
            *(float4*)&bs[0] = *(const float4*)&sb_s [kk][tx * 4];
            *(float4*)&bm[0] = *(const float4*)&sb_ms[kk][tx * 4];
            #pragma unroll
            for (int i = 0; i < 8; ++i)
                #pragma unroll
                for (int j = 0; j < 4; ++j)
                    acc[i][j] += a2[i] * bs[j] + az[i] * bm[j];
        }
        __syncthreads();
    }
    // ---- epilogue: += nc14, store
    const float4 c4 = *(const float4*)(nc14 + b * TX + n0 + tx * 4);
    float* ob = out + (size_t)b * TY * TX + (size_t)m0 * TX + n0 + tx * 4;
    #pragma unroll
    for (int i = 0; i < 8; ++i) {
        float4 r;
        r.x = acc[i][0] + c4.x; r.y = acc[i][1] + c4.y;
        r.z = acc[i][2] + c4.z; r.w = acc[i][3] + c4.w;
        *(float4*)(ob + (size_t)(ty * 8 + i) * TX) = r;
    }
}

// ======================= K3: DP (forward + backtrack) =======================
// One 64-lane wave per batch. Lane owns x in [8*lane, 8*lane+8).
// Forward: cum in registers, per-row diag-bits (cum[y-1][x] < cum[y-1][x-1])
// packed 8/lane and stored into the first 64 bytes of attn row y (clobbered
// later, strictly after being consumed). Backtrack: 32-row chunks, 64-bit
// bit-window per row fetched in parallel across lanes, serial resolve via
// register shuffles. Durations in LDS, logw at the end.
__global__ __launch_bounds__(64, 1)
void dp_kernel(float* __restrict__ out,
               const int* __restrict__ t_xs,
               const int* __restrict__ t_ys) {
    const size_t PLANE = (size_t)TY * TX;
    const size_t OFF1  = (size_t)B_ * PLANE;
    const size_t OFF2  = 2 * OFF1;

    const int b    = blockIdx.x;
    const int lane = threadIdx.x;
    const int t_x  = t_xs[b];
    const int t_y  = t_ys[b];

    const float* nc   = out + (size_t)b * PLANE;
    float*       attn = out + OFF1 + (size_t)b * PLANE;
    float*       logw = out + OFF2 + (size_t)b * TX;
    unsigned char* bitsb = (unsigned char*)attn;

    __shared__ int w_lds[TX];
    for (int i = lane; i < TX; i += 64) w_lds[i] = 0;

    // ---------------- forward ----------------
    float cum[8];
    {
        float4 v0 = *(const float4*)(nc + lane * 8);
        #pragma unroll
        for (int j = 0; j < 8; ++j) cum[j] = NEG_INF_F;
        if (lane == 0) cum[0] = v0.x;
    }

    auto step = [&](int yy, float4 va, float4 vb) {
        float up  = __shfl_up(cum[7], 1, 64);
        float sh0 = (lane == 0) ? NEG_INF_F : up;
        unsigned bits = (cum[0] < sh0) ? 1u : 0u;
        #pragma unroll
        for (int j = 1; j < 8; ++j)
            bits |= (cum[j] < cum[j - 1]) ? (1u << j) : 0u;
        float v[8] = {va.x, va.y, va.z, va.w, vb.x, vb.y, vb.z, vb.w};
        float c0 = v[0] + fmaxf(cum[0], sh0);
        #pragma unroll
        for (int j = 7; j >= 1; --j)          // descending: uses old cum[j-1]
            cum[j] = v[j] + fmaxf(cum[j], cum[j - 1]);
        cum[0] = c0;
        bitsb[(size_t)yy * 2048 + lane] = (unsigned char)bits;
    };

    float4 bufA[16], bufB[16];
    auto loadGroup = [&](float4* buf, int ybase) {
        #pragma unroll
        for (int r = 0; r < 8; ++r) {
            int yy = ybase + r;
            if (yy > t_y - 1) yy = t_y - 1;
            const float* p = nc + (size_t)yy * TX + lane * 8;
            buf[2 * r]     = *(const float4*)p;
            buf[2 * r + 1] = *(const float4*)(p + 4);
        }
    };
    loadGroup(bufA, 1);
    loadGroup(bufB, 9);

    int y = 1, g = 0;
    while (y + 8 <= t_y) {
        float4* cur = (g & 1) ? bufB : bufA;
        #pragma unroll
        for (int r = 0; r < 8; ++r) step(y + r, cur[2 * r], cur[2 * r + 1]);
        loadGroup(cur, y + 16);
        y += 8; g ^= 1;
    }
    for (; y < t_y; ++y) {
        const float* p = nc + (size_t)y * TX + lane * 8;
        step(y, *(const float4*)p, *(const float4*)(p + 4));
    }

    // ---------------- zero rows >= t_y ----------------
    {
        float4 z4; z4.x = z4.y = z4.z = z4.w = 0.f;
        for (int yy = t_y; yy < TY; ++yy) {
            float* p = attn + (size_t)yy * TX + lane * 8;
            *(float4*)p = z4;
            *(float4*)(p + 4) = z4;
        }
    }

    // ---------------- backtrack ----------------
    int idx  = t_x - 1;
    int yhi  = t_y - 1;
    int ytop = t_y - 1;
    while (ytop >= 0) {
        int cnt = (ytop >= 31) ? 32 : (ytop + 1);
        int wh  = idx >> 5;
        int wlo = (wh > 0) ? wh - 1 : 0;
        unsigned vlo = 0u, vhi = 0u;
        if (lane < cnt) {
            const unsigned* rp = (const unsigned*)attn + (size_t)(ytop - lane) * TX;
            vlo = rp[wlo];
            vhi = rp[wh];
        }
        int base = wlo * 32;
        for (int i = 0; i < cnt; ++i) {
            int yy = ytop - i;
            unsigned lo = __shfl(vlo, i, 64);   // forces vmcnt drain before stores
            unsigned hi = __shfl(vhi, i, 64);
            // one-hot attn row (clobbers this row's bits, already consumed)
            int x0 = lane * 8;
            float4 r0, r1;
            r0.x = (x0 + 0 == idx) ? 1.f : 0.f;
            r0.y = (x0 + 1 == idx) ? 1.f : 0.f;
            r0.z = (x0 + 2 == idx) ? 1.f : 0.f;
            r0.w = (x0 + 3 == idx) ? 1.f : 0.f;
            r1.x = (x0 + 4 == idx) ? 1.f : 0.f;
            r1.y = (x0 + 5 == idx) ? 1.f : 0.f;
            r1.z = (x0 + 6 == idx) ? 1.f : 0.f;
            r1.w = (x0 + 7 == idx) ? 1.f : 0.f;
            float* p = attn + (size_t)yy * TX + x0;
            *(float4*)p = r0;
            *(float4*)(p + 4) = r1;
            // move decision (uniform across lanes)
            unsigned long long V = ((unsigned long long)hi << 32) | lo;
            int pos   = idx - base;
            int bit   = (int)((V >> pos) & 1ull);
            int force = (idx == yy) ? 1 : 0;
            int move  = (force | bit) & ((idx > 0) ? 1 : 0) & ((yy > 0) ? 1 : 0);
            if (move) {
                if (lane == 0) w_lds[idx] = yhi - yy + 1;
                yhi = yy - 1;
                idx -= 1;
            }
        }
        ytop -= cnt;
    }
    if (lane == 0) w_lds[idx] = yhi + 1;   // phoneme holding row 0
    __syncthreads();

    // ---------------- logw ----------------
    #pragma unroll
    for (int j = 0; j < 8; ++j) {
        int x = lane + 64 * j;
        float v = (x < t_x) ? logf((float)w_lds[x] + 1e-6f) : 0.f;
        logw[x] = v;
    }
}

// ======================= launch =======================
extern "C" void kernel_launch(void* const* d_in, const int* in_sizes, int n_in,
                              void* d_out, int out_size, void* d_ws, size_t ws_size,
                              hipStream_t stream) {
    const float* z_p    = (const float*)d_in[0];
    const float* m_p    = (const float*)d_in[1];
    const float* logs_p = (const float*)d_in[2];
    const int* ph_len   = (const int*)d_in[3];
    const int* mel_len  = (const int*)d_in[4];
    float* out  = (float*)d_out;
    float* nc14 = (float*)d_ws;   // 16*512 floats = 32 KB scratch

    nc14_kernel<<<(B_ * TX) / 256, 256, 0, stream>>>(m_p, logs_p, nc14);
    gemm_kernel<<<dim3(TX / BN, TY / BM, B_), 256, 0, stream>>>(z_p, m_p, logs_p, nc14, out);
    dp_kernel<<<B_, 64, 0, stream>>>(out, ph_len, mel_len);
}

// Round 2
// 953.983 us; speedup vs baseline: 2.1732x; 2.1732x over previous
//
#include <hip/hip_runtime.h>
#include <cstdint>
#include <cstddef>

#define B_   16
#define D_   192
#define TY   2048
#define TX   512
#define NEG_INF_F (-1e9f)

// ======================= K1: nc14[b,x] = nc1 + nc4 =======================
__global__ __launch_bounds__(256)
void nc14_kernel(const float* __restrict__ m_p,
                 const float* __restrict__ logs_p,
                 float* __restrict__ nc14) {
    int gid = blockIdx.x * 256 + threadIdx.x;       // 0..8191  (B*TX)
    int b = gid >> 9;
    int x = gid & 511;
    const float c = -0.9189385332046727f;           // -0.5*log(2*pi)
    const float* lp = logs_p + (size_t)b * D_ * TX + x;
    const float* mp = m_p    + (size_t)b * D_ * TX + x;
    float acc1 = 0.f, acc2 = 0.f;
    for (int d = 0; d < D_; ++d) {
        float l = lp[(size_t)d * TX];
        float m = mp[(size_t)d * TX];
        float s = __expf(-2.f * l);
        acc1 += c - l;
        acc2 += m * m * s;
    }
    nc14[gid] = acc1 - 0.5f * acc2;
}

// ======================= K2: fp32 GEMM for neg_cent =======================
// C[b,y,x] = nc14[b,x] + sum_d( (-0.5 z^2)[d,y]*s[d,x] + z[d,y]*(m*s)[d,x] )
#define BM 128
#define BN 64
#define BK 16

__global__ __launch_bounds__(256)
void gemm_kernel(const float* __restrict__ z_p,
                 const float* __restrict__ m_p,
                 const float* __restrict__ logs_p,
                 const float* __restrict__ nc14,
                 float* __restrict__ out) {
    __shared__ float a_z [BK][BM];
    __shared__ float a_z2[BK][BM];
    __shared__ float sb_s [BK][BN];
    __shared__ float sb_ms[BK][BN];

    const int b  = blockIdx.z;
    const int m0 = blockIdx.y * BM;
    const int n0 = blockIdx.x * BN;
    const int tid = threadIdx.x;
    const int tx = tid & 15;      // 16 cols-of-4
    const int ty = tid >> 4;      // 16 rows-of-8

    const float* zb = z_p    + (size_t)b * D_ * TY;
    const float* mb = m_p    + (size_t)b * D_ * TX;
    const float* lb = logs_p + (size_t)b * D_ * TX;

    float acc[8][4];
    #pragma unroll
    for (int i = 0; i < 8; ++i)
        #pragma unroll
        for (int j = 0; j < 4; ++j) acc[i][j] = 0.f;

    for (int k0 = 0; k0 < D_; k0 += BK) {
        #pragma unroll
        for (int q = 0; q < 2; ++q) {
            int idx = tid * 2 + q;            // 0..511
            int kk = idx >> 5;                // 16 rows
            int yy = (idx & 31) * 4;          // 128 cols
            float4 v = *(const float4*)(zb + (size_t)(k0 + kk) * TY + m0 + yy);
            *(float4*)&a_z[kk][yy] = v;
            float4 w;
            w.x = -0.5f * v.x * v.x; w.y = -0.5f * v.y * v.y;
            w.z = -0.5f * v.z * v.z; w.w = -0.5f * v.w * v.w;
            *(float4*)&a_z2[kk][yy] = w;
        }
        {
            int kk = tid >> 4;
            int xx = (tid & 15) * 4;
            float4 lg = *(const float4*)(lb + (size_t)(k0 + kk) * TX + n0 + xx);
            float4 mm = *(const float4*)(mb + (size_t)(k0 + kk) * TX + n0 + xx);
            float4 s;
            s.x = __expf(-2.f * lg.x); s.y = __expf(-2.f * lg.y);
            s.z = __expf(-2.f * lg.z); s.w = __expf(-2.f * lg.w);
            *(float4*)&sb_s[kk][xx] = s;
            float4 ms;
            ms.x = mm.x * s.x; ms.y = mm.y * s.y;
            ms.z = mm.z * s.z; ms.w = mm.w * s.w;
            *(float4*)&sb_ms[kk][xx] = ms;
        }
        __syncthreads();
        #pragma unroll
        for (int kk = 0; kk < BK; ++kk) {
            float az[8], a2[8], bs[4], bm[4];
            *(float4*)&az[0] = *(const float4*)&a_z [kk][ty * 8];
            *(float4*)&az[4] = *(const float4*)&a_z [kk][ty * 8 + 4];
            *(float4*)&a2[0] = *(const float4*)&a_z2[kk][ty * 8];
            *(float4*)&a2[4] = *(const float4*)&a_z2[kk][ty * 8 + 4];
            *(float4*)&bs[0] = *(const float4*)&sb_s [kk][tx * 4];
            *(float4*)&bm[0] = *(const float4*)&sb_ms[kk][tx * 4];
            #pragma unroll
            for (int i = 0; i < 8; ++i)
                #pragma unroll
                for (int j = 0; j < 4; ++j)
                    acc[i][j] += a2[i] * bs[j] + az[i] * bm[j];
        }
        __syncthreads();
    }
    const float4 c4 = *(const float4*)(nc14 + b * TX + n0 + tx * 4);
    float* ob = out + (size_t)b * TY * TX + (size_t)m0 * TX + n0 + tx * 4;
    #pragma unroll
    for (int i = 0; i < 8; ++i) {
        float4 r;
        r.x = acc[i][0] + c4.x; r.y = acc[i][1] + c4.y;
        r.z = acc[i][2] + c4.z; r.w = acc[i][3] + c4.w;
        *(float4*)(ob + (size_t)(ty * 8 + i) * TX) = r;
    }
}

// ======================= K3: DP (forward + backtrack) =======================
// One 64-lane wave per batch; lane owns x in [8*lane, 8*lane+8).
// Forward: cum in registers; per-row diag-bits (cum[y-1][x] < cum[y-1][x-1])
// packed 8/lane, stored (64 B/row) into attn row y (consumed by backtrack,
// then overwritten wholesale by attn_fill). Double-buffered register prefetch
// with COMPILE-TIME buffer identity — R0's runtime pointer swap demoted the
// buffers to scratch (VGPR_Count=24!) and cost 10x in latency.
// Backtrack: emits durations only (no attn writes); prefix-sum -> cumE in ws;
// logw written directly.
__global__ __launch_bounds__(64, 1)
void dp_kernel(float* __restrict__ out,
               const int* __restrict__ t_xs,
               const int* __restrict__ t_ys,
               int* __restrict__ cumE) {
    const size_t PLANE = (size_t)TY * TX;
    const size_t OFF1  = (size_t)B_ * PLANE;
    const size_t OFF2  = 2 * OFF1;

    const int b    = blockIdx.x;
    const int lane = threadIdx.x;
    const int t_x  = t_xs[b];
    const int t_y  = t_ys[b];
    const int tym1 = t_y - 1;

    const float* nc   = out + (size_t)b * PLANE;
    float*       attn = out + OFF1 + (size_t)b * PLANE;
    float*       logw = out + OFF2 + (size_t)b * TX;
    unsigned char* bitsb = (unsigned char*)attn;

    __shared__ int w_lds[TX];
    for (int i = lane; i < TX; i += 64) w_lds[i] = 0;

    // ---------------- forward ----------------
    float cum[8];
    {
        float4 v0 = *(const float4*)(nc + lane * 8);
        #pragma unroll
        for (int j = 0; j < 8; ++j) cum[j] = NEG_INF_F;
        if (lane == 0) cum[0] = v0.x;
    }

    auto step = [&](int yy, float4 va, float4 vb) {
        float up  = __shfl_up(cum[7], 1, 64);
        float sh0 = (lane == 0) ? NEG_INF_F : up;
        unsigned bits = (cum[0] < sh0) ? 1u : 0u;
        #pragma unroll
        for (int j = 1; j < 8; ++j)
            bits |= (cum[j] < cum[j - 1]) ? (1u << j) : 0u;
        float v[8] = {va.x, va.y, va.z, va.w, vb.x, vb.y, vb.z, vb.w};
        float c0 = v[0] + fmaxf(cum[0], sh0);
        #pragma unroll
        for (int j = 7; j >= 1; --j)          // descending: uses old cum[j-1]
            cum[j] = v[j] + fmaxf(cum[j], cum[j - 1]);
        cum[0] = c0;
        bitsb[(size_t)yy * 2048 + lane] = (unsigned char)bits;
    };

    float4 bufA[16], bufB[16];

#define LOAD_GROUP(BUF, YBASE)                                              \
    do {                                                                    \
        _Pragma("unroll")                                                   \
        for (int r = 0; r < 8; ++r) {                                       \
            int yy = (YBASE) + r;                                           \
            if (yy > tym1) yy = tym1;                                       \
            const float* p = nc + (size_t)yy * TX + lane * 8;               \
            BUF[2 * r]     = *(const float4*)p;                             \
            BUF[2 * r + 1] = *(const float4*)(p + 4);                       \
        }                                                                   \
    } while (0)

#define STEP_GROUP(BUF, YBASE)                                              \
    do {                                                                    \
        _Pragma("unroll")                                                   \
        for (int r = 0; r < 8; ++r)                                         \
            step((YBASE) + r, BUF[2 * r], BUF[2 * r + 1]);                  \
    } while (0)

    LOAD_GROUP(bufA, 1);
    LOAD_GROUP(bufB, 9);

    int y = 1;
    while (y + 16 <= t_y) {
        STEP_GROUP(bufA, y);
        LOAD_GROUP(bufA, y + 16);
        STEP_GROUP(bufB, y + 8);
        LOAD_GROUP(bufB, y + 24);
        y += 16;
    }
    if (y + 8 <= t_y) {               // bufA holds rows [y, y+8)
        STEP_GROUP(bufA, y);
        y += 8;
    }
    for (; y < t_y; ++y) {
        const float* p = nc + (size_t)y * TX + lane * 8;
        step(y, *(const float4*)p, *(const float4*)(p + 4));
    }
#undef LOAD_GROUP
#undef STEP_GROUP

    // ---------------- backtrack (durations only) ----------------
    int idx  = t_x - 1;
    int yhi  = t_y - 1;
    int ytop = t_y - 1;
    while (ytop >= 0) {
        int cnt = (ytop >= 31) ? 32 : (ytop + 1);
        int wh  = idx >> 5;
        int wlo = (wh > 0) ? wh - 1 : 0;
        unsigned vlo = 0u, vhi = 0u;
        if (lane < cnt) {
            const unsigned* rp = (const unsigned*)attn + (size_t)(ytop - lane) * TX;
            vlo = rp[wlo];
            vhi = rp[wh];
        }
        int base = wlo * 32;
        for (int i = 0; i < cnt; ++i) {
            int yy = ytop - i;
            unsigned lo = __shfl(vlo, i, 64);
            unsigned hi = __shfl(vhi, i, 64);
            unsigned long long V = ((unsigned long long)hi << 32) | lo;
            int pos   = idx - base;
            int bit   = (int)((V >> pos) & 1ull);
            int force = (idx == yy) ? 1 : 0;
            int move  = (force | bit) & ((idx > 0) ? 1 : 0) & ((yy > 0) ? 1 : 0);
            if (move) {
                if (lane == 0) w_lds[idx] = yhi - yy + 1;
                yhi = yy - 1;
                idx -= 1;
            }
        }
        ytop -= cnt;
    }
    if (lane == 0) w_lds[idx] = yhi + 1;   // phoneme holding row 0
    __syncthreads();

    // ---------------- logw + prefix-sum -> cumE ----------------
    int v[8];
    int run = 0;
    #pragma unroll
    for (int j = 0; j < 8; ++j) {
        int wv = w_lds[lane * 8 + j];
        run += wv;
        v[j] = run;                   // inclusive within lane
    }
    int off = run;
    #pragma unroll
    for (int d = 1; d < 64; d <<= 1) {
        int t = __shfl_up(off, d, 64);
        if (lane >= d) off += t;
    }
    int excl = off - run;             // exclusive across lanes
    #pragma unroll
    for (int j = 0; j < 8; ++j) {
        int x = lane * 8 + j;
        cumE[b * TX + x] = v[j] + excl;
        int wv = w_lds[x];
        logw[x] = (x < t_x) ? logf((float)wv + 1e-6f) : 0.f;
    }
}

// ======================= K4: attn one-hot fill =======================
// attn[b,y,x] = 1 iff cs[x] <= y < cs[x+1] where cs is the exclusive
// duration prefix-sum. Rows y >= t_y and phonemes x >= t_x fall out as 0
// automatically (cs values are capped at t_y / constant beyond t_x).
__global__ __launch_bounds__(256)
void attn_fill_kernel(const int* __restrict__ cumE,
                      float* __restrict__ out) {
    const size_t PLANE = (size_t)TY * TX;
    const size_t OFF1  = (size_t)B_ * PLANE;
    __shared__ int cs[TX + 1];
    const int b  = blockIdx.y;
    const int y0 = blockIdx.x * 4;
    const int t  = threadIdx.x;
    if (t == 0) cs[0] = 0;
    cs[1 + t]       = cumE[b * TX + t];
    cs[1 + 256 + t] = cumE[b * TX + 256 + t];
    __syncthreads();
    const int y  = y0 + (t >> 6);
    const int x0 = (t & 63) * 8;
    float r[8];
    #pragma unroll
    for (int j = 0; j < 8; ++j)
        r[j] = (cs[x0 + j] <= y && y < cs[x0 + j + 1]) ? 1.f : 0.f;
    float* p = out + OFF1 + (size_t)b * PLANE + (size_t)y * TX + x0;
    *(float4*)p       = *(float4*)&r[0];
    *(float4*)(p + 4) = *(float4*)&r[4];
}

// ======================= launch =======================
extern "C" void kernel_launch(void* const* d_in, const int* in_sizes, int n_in,
                              void* d_out, int out_size, void* d_ws, size_t ws_size,
                              hipStream_t stream) {
    const float* z_p    = (const float*)d_in[0];
    const float* m_p    = (const float*)d_in[1];
    const float* logs_p = (const float*)d_in[2];
    const int* ph_len   = (const int*)d_in[3];
    const int* mel_len  = (const int*)d_in[4];
    float* out  = (float*)d_out;
    float* nc14 = (float*)d_ws;          // 16*512 floats = 32 KB
    int*   cumE = (int*)d_ws;            // reuses nc14's space (dead after gemm)

    nc14_kernel<<<(B_ * TX) / 256, 256, 0, stream>>>(m_p, logs_p, nc14);
    gemm_kernel<<<dim3(TX / BN, TY / BM, B_), 256, 0, stream>>>(z_p, m_p, logs_p, nc14, out);
    dp_kernel<<<B_, 64, 0, stream>>>(out, ph_len, mel_len, cumE);
    attn_fill_kernel<<<dim3(TY / 4, B_), 256, 0, stream>>>(cumE, out);
}